// Round 17
// baseline (95.875 us; speedup 1.0000x reference)
//
#include <hip/hip_runtime.h>
#include <math.h>

#define B 8
#define C 512
#define L 8192
#define N 512      // L/CS chunk steps
#define C8 64      // C/8 bottleneck dim
#define CT1 4      // channels per pool_ema block (grid 1024 = 4/CU)
#define STR1 577   // cm per-channel stride (64 seg x 9)
#define NT2 4      // chunk rows per se_apply block
#define GS2 260    // gate LDS row stride

// round-to-nearest-even fp32 -> bf16 (as uint16 in low bits)
__device__ __forceinline__ unsigned bf16rne(float f) {
    unsigned u = __float_as_uint(f);
    return (u + 0x7FFFu + ((u >> 16) & 1u)) >> 16;
}
__device__ __forceinline__ float bf16f(unsigned h) {
    return __uint_as_float(h << 16);
}

// ---------------------------------------------------------------------------
// Kernel 1: fused pooling + full causal EMA + bf16 shadow write.
// x [B,C,L] -> e [B,N,C], xb [B,C,L] bf16 (written from the registers that
// already hold x for pooling -> zero extra reads).
// ---------------------------------------------------------------------------
__global__ __launch_bounds__(256) void pool_ema_k(
    const float* __restrict__ x, const float* __restrict__ gamma,
    float* __restrict__ e, unsigned short* __restrict__ xb,
    const float* __restrict__ w1, const float* __restrict__ w2,
    float* __restrict__ w1t4, float* __restrict__ w2t4) {
    __shared__ float cm[CT1 * STR1];       // 9.2 KB: cl*577 + s*9 + i
    __shared__ float carry_s[CT1 * 64];
    __shared__ float pre_s[CT1 * 64];
    const int t = threadIdx.x;
    const int bid = blockIdx.x;            // B * 128 = 1024
    const int ct = bid & 127;
    const int b = bid >> 7;

    // weight repack (first 128 blocks' threads)
    const int gid = bid * 256 + t;
    if (gid < C8 * C) {
        const int o = gid >> 9, k = gid & (C - 1);
        w1t4[((k >> 2) * C8 + o) * 4 + (k & 3)] = w1[gid];
        const int c2 = gid >> 6, k2 = gid & (C8 - 1);
        w2t4[((k2 >> 2) * C + c2) * 4 + (k2 & 3)] = w2[gid];
    }

    const int w = t >> 6, lane = t & 63;
    // ---- Phase A: chunk means + bf16 shadow store (wave w = channel w) ----
    {
        const size_t row4 = (size_t)(b * C + ct * CT1 + w) * (L / 4);
        uint2* xb2 = reinterpret_cast<uint2*>(xb);
#pragma unroll
        for (int rr = 0; rr < 4; ++rr) {
            float4 f[8];
#pragma unroll
            for (int u = 0; u < 8; ++u)
                f[u] = reinterpret_cast<const float4*>(x)[row4 + rr * 512 + u * 64 + lane];
#pragma unroll
            for (int u = 0; u < 8; ++u) {
                // bf16 shadow (coalesced 8 B/lane at the same float4 index)
                uint2 pk;
                pk.x = bf16rne(f[u].x) | (bf16rne(f[u].y) << 16);
                pk.y = bf16rne(f[u].z) | (bf16rne(f[u].w) << 16);
                xb2[row4 + rr * 512 + u * 64 + lane] = pk;

                float s = f[u].x + f[u].y + f[u].z + f[u].w;
                s += __shfl_down(s, 1, 4);
                s += __shfl_down(s, 2, 4);
                if ((lane & 3) == 0) {
                    const int chunk = rr * 128 + u * 16 + (lane >> 2);
                    cm[w * STR1 + (chunk >> 3) * 9 + (chunk & 7)] = s * (1.0f / 16.0f);
                }
            }
        }
    }
    __syncthreads();

    // ---- Phase B: EMA scan. thread = (cl = t>>6, s = t&63), 8 steps each ----
    const int cl = t >> 6, s = t & 63;
    const float g = gamma[ct * CT1 + cl];
    const float omg = 1.0f - g;
    {
        float y = 0.0f;
#pragma unroll
        for (int i = 0; i < 8; ++i)
            y = fmaf(g, y, omg * cm[cl * STR1 + s * 9 + i]);
        carry_s[cl * 64 + s] = y;
    }
    __syncthreads();
    if (t < CT1) {
        const float gg = gamma[ct * CT1 + t];
        float g8 = gg * gg; g8 *= g8; g8 *= g8;            // g^8
        float E = 0.0f;
#pragma unroll
        for (int ss = 0; ss < 64; ++ss) {
            pre_s[t * 64 + ss] = E;
            E = fmaf(g8, E, carry_s[t * 64 + ss]);
        }
    }
    __syncthreads();
    {
        float y = pre_s[cl * 64 + s];
#pragma unroll
        for (int i = 0; i < 8; ++i) {
            y = fmaf(g, y, omg * cm[cl * STR1 + s * 9 + i]);
            cm[cl * STR1 + s * 9 + i] = y;
        }
    }
    __syncthreads();

    // ---- write e [B,N,C] ----
    float* ebase = e + (size_t)b * N * C + ct * CT1;
#pragma unroll
    for (int rr = 0; rr < 8; ++rr) {
        const int idx = rr * 256 + t;
        const int n = idx >> 2, c2 = idx & 3;
        ebase[(size_t)n * C + c2] = cm[c2 * STR1 + (n >> 3) * 9 + (n & 7)];
    }
}

// ---------------------------------------------------------------------------
// Kernel 2: fused SE + apply, c-half split. Apply reads the bf16 shadow
// (75 MB total, L3-resident by capacity: xb+e+out = 209 MB < 256 MB).
// ---------------------------------------------------------------------------
__global__ __launch_bounds__(256) void se_apply_k(
    const float* __restrict__ e, const float* __restrict__ w1t4,
    const float* __restrict__ b1, const float* __restrict__ w2t4,
    const float* __restrict__ b2, const unsigned short* __restrict__ xb,
    float* __restrict__ out) {
    __shared__ float es[NT2 * C];          // 8 KB
    __shared__ float hs[NT2 * C8];         // 1 KB
    __shared__ float red[4 * NT2 * C8];    // 4 KB  [j][r][o]
    __shared__ float gs[NT2 * GS2];        // 4.2 KB (256 c-rows)
    const int t = threadIdx.x;
    const int bid = blockIdx.x;            // B * 128 * 2 = 2048
    const int chalf = bid & 1;
    const int nt = (bid >> 1) & 127;
    const int b = bid >> 8;
    const int n0 = nt * NT2;

    // stage e rows n0..n0+3 (coalesced; full C needed for GEMM1)
    {
        const float4* esrc = reinterpret_cast<const float4*>(e + ((size_t)b * N + n0) * C);
        float4* esw = reinterpret_cast<float4*>(es);
        esw[t] = esrc[t];
        esw[256 + t] = esrc[256 + t];
    }
    __syncthreads();

    // GEMM1 k-split: j = k-quarter (wave-uniform), o = lane. w1 once/block.
    {
        const int o = t & 63, j = t >> 6;
        float a0 = 0.f, a1 = 0.f, a2 = 0.f, a3 = 0.f;
        const float4* w1v = reinterpret_cast<const float4*>(w1t4);
        const float4* es4 = reinterpret_cast<const float4*>(es);
        const int k40 = j * 32;
#pragma unroll 8
        for (int kk = 0; kk < 32; ++kk) {
            const int k4 = k40 + kk;
            const float4 wv = w1v[k4 * C8 + o];
            const float4 e0 = es4[0 * 128 + k4];
            const float4 e1 = es4[1 * 128 + k4];
            const float4 e2 = es4[2 * 128 + k4];
            const float4 e3 = es4[3 * 128 + k4];
            a0 = fmaf(wv.x, e0.x, a0); a0 = fmaf(wv.y, e0.y, a0);
            a0 = fmaf(wv.z, e0.z, a0); a0 = fmaf(wv.w, e0.w, a0);
            a1 = fmaf(wv.x, e1.x, a1); a1 = fmaf(wv.y, e1.y, a1);
            a1 = fmaf(wv.z, e1.z, a1); a1 = fmaf(wv.w, e1.w, a1);
            a2 = fmaf(wv.x, e2.x, a2); a2 = fmaf(wv.y, e2.y, a2);
            a2 = fmaf(wv.z, e2.z, a2); a2 = fmaf(wv.w, e2.w, a2);
            a3 = fmaf(wv.x, e3.x, a3); a3 = fmaf(wv.y, e3.y, a3);
            a3 = fmaf(wv.z, e3.z, a3); a3 = fmaf(wv.w, e3.w, a3);
        }
        red[(j * 4 + 0) * 64 + o] = a0;
        red[(j * 4 + 1) * 64 + o] = a1;
        red[(j * 4 + 2) * 64 + o] = a2;
        red[(j * 4 + 3) * 64 + o] = a3;
    }
    __syncthreads();
    {
        const int o = t & 63, r = t >> 6;
        const float h = red[(0 * 4 + r) * 64 + o] + red[(1 * 4 + r) * 64 + o]
                      + red[(2 * 4 + r) * 64 + o] + red[(3 * 4 + r) * 64 + o];
        hs[r * C8 + o] = fmaxf(h + b1[o], 0.f);
    }
    __syncthreads();

    // GEMM2 + sigmoid -> gs[4][256] (this block's c-half only).
    {
        const int c = chalf * 256 + t;
        float acc[NT2];
        const float bb = b2[c];
#pragma unroll
        for (int j = 0; j < NT2; ++j) acc[j] = bb;
        const float4* w2v = reinterpret_cast<const float4*>(w2t4);
        const float4* hs4 = reinterpret_cast<const float4*>(hs);
#pragma unroll
        for (int k4 = 0; k4 < 16; ++k4) {
            const float4 wa = w2v[k4 * C + c];
#pragma unroll
            for (int j = 0; j < NT2; ++j) {
                const float4 hv = hs4[j * 16 + k4];
                acc[j] = fmaf(wa.x, hv.x, acc[j]); acc[j] = fmaf(wa.y, hv.y, acc[j]);
                acc[j] = fmaf(wa.z, hv.z, acc[j]); acc[j] = fmaf(wa.w, hv.w, acc[j]);
            }
        }
#pragma unroll
        for (int j = 0; j < NT2; ++j)
            gs[j * GS2 + t] = 1.0f / (1.0f + __expf(-acc[j]));
    }
    __syncthreads();

    // apply: 256 c-rows (this half), l-range [nt*64, nt*64+64).
    // read bf16 shadow in 8-value groups (uint4 = 16 B/lane, coalesced),
    // write 2x float4 (32 B/lane, contiguous across lanes).
    {
        const size_t base8 = (size_t)b * C * (L / 8) + nt * 8;   // uint4 units
        const size_t base4 = (size_t)b * C * (L / 4) + nt * 16;  // float4 units
        const uint4* xb4 = reinterpret_cast<const uint4*>(xb);
        float4* o4 = reinterpret_cast<float4*>(out);
#pragma unroll 8
        for (int i = 0; i < 8; ++i) {
            const int p = i * 256 + t;     // 2048 groups of 8 values
            const int rloc = p >> 3;       // local c row 0..255
            const int q = p & 7;           // 8-float group within 64-f segment
            const float g = gs[(q >> 1) * GS2 + rloc];
            const uint4 d = xb4[base8 + (size_t)(chalf * 256 + rloc) * (L / 8) + q];
            float4 v0, v1;
            v0.x = bf16f(d.x & 0xFFFFu) * g;  v0.y = bf16f(d.x >> 16) * g;
            v0.z = bf16f(d.y & 0xFFFFu) * g;  v0.w = bf16f(d.y >> 16) * g;
            v1.x = bf16f(d.z & 0xFFFFu) * g;  v1.y = bf16f(d.z >> 16) * g;
            v1.z = bf16f(d.w & 0xFFFFu) * g;  v1.w = bf16f(d.w >> 16) * g;
            const size_t oidx = base4 + (size_t)(chalf * 256 + rloc) * (L / 4) + q * 2;
            o4[oidx]     = v0;
            o4[oidx + 1] = v1;
        }
    }
}

// ---------------------------------------------------------------------------
extern "C" void kernel_launch(void* const* d_in, const int* in_sizes, int n_in,
                              void* d_out, int out_size, void* d_ws, size_t ws_size,
                              hipStream_t stream) {
    const float* x     = (const float*)d_in[0];
    const float* gamma = (const float*)d_in[1];
    const float* w1    = (const float*)d_in[2];
    const float* b1    = (const float*)d_in[3];
    const float* w2    = (const float*)d_in[4];
    const float* b2    = (const float*)d_in[5];
    float* out = (float*)d_out;

    char* ws = (char*)d_ws;
    size_t off = 0;
    float* e    = (float*)(ws + off); off += (size_t)B * N * C * 4;      // 8 MB
    float* w1t4 = (float*)(ws + off); off += (size_t)C8 * C * 4;         // 128 KB
    float* w2t4 = (float*)(ws + off); off += (size_t)C8 * C * 4;         // 128 KB
    unsigned short* xb = (unsigned short*)(ws + off);
    off += (size_t)B * C * L * 2;                                        // 67 MB

    // K1: fused pooling + EMA -> e; bf16 shadow of x -> xb (from registers)
    pool_ema_k<<<B * 128, 256, 0, stream>>>(x, gamma, e, xb, w1, w2, w1t4, w2t4);
    // K2: fused SE (gate in LDS) + apply from bf16 shadow (L3-resident)
    se_apply_k<<<B * 256, 256, 0, stream>>>(e, w1t4, b1, w2t4, b2, xb, out);
}

// Round 18
// 77.606 us; speedup vs baseline: 1.2354x; 1.2354x over previous
//
#include <hip/hip_runtime.h>
#include <math.h>

#define B 8
#define C 512
#define L 8192
#define N 512      // L/CS chunk steps
#define C8 64      // C/8 bottleneck dim
#define CT1 4      // channels per pool_ema block (grid 1024 = 4/CU)
#define STR1 577   // cm per-channel stride (64 seg x 9)
#define NT2 4      // chunk rows per se_apply block
#define GS2 260    // gate LDS row stride

// ---------------------------------------------------------------------------
// Kernel 1: fused pooling + full causal EMA.  x [B,C,L] -> e [B][128][N][4]
// (block-local e layout: each block writes its 8 KB contiguously, fully
// coalesced full-line stores -- was 16 B granules at 2 KB stride assembled
// cross-XCD). Also folds in the tiny weight re-pack.
// ---------------------------------------------------------------------------
__global__ __launch_bounds__(256) void pool_ema_k(
    const float* __restrict__ x, const float* __restrict__ gamma,
    float* __restrict__ e,
    const float* __restrict__ w1, const float* __restrict__ w2,
    float* __restrict__ w1t4, float* __restrict__ w2t4) {
    __shared__ float cm[CT1 * STR1];       // 9.2 KB: cl*577 + s*9 + i
    __shared__ float carry_s[CT1 * 64];
    __shared__ float pre_s[CT1 * 64];
    const int t = threadIdx.x;
    const int bid = blockIdx.x;            // B * 128 = 1024
    const int ct = bid & 127;
    const int b = bid >> 7;

    // weight repack (first 128 blocks' threads)
    const int gid = bid * 256 + t;
    if (gid < C8 * C) {
        const int o = gid >> 9, k = gid & (C - 1);
        w1t4[((k >> 2) * C8 + o) * 4 + (k & 3)] = w1[gid];
        const int c2 = gid >> 6, k2 = gid & (C8 - 1);
        w2t4[((k2 >> 2) * C + c2) * 4 + (k2 & 3)] = w2[gid];
    }

    const int w = t >> 6, lane = t & 63;
    // ---- Phase A: chunk means. wave w = channel w (4 waves, 4 channels) ----
    {
        const size_t row4 = (size_t)(b * C + ct * CT1 + w) * (L / 4);
#pragma unroll
        for (int rr = 0; rr < 4; ++rr) {
            float4 f[8];
#pragma unroll
            for (int u = 0; u < 8; ++u)
                f[u] = reinterpret_cast<const float4*>(x)[row4 + rr * 512 + u * 64 + lane];
#pragma unroll
            for (int u = 0; u < 8; ++u) {
                float s = f[u].x + f[u].y + f[u].z + f[u].w;
                s += __shfl_down(s, 1, 4);
                s += __shfl_down(s, 2, 4);
                if ((lane & 3) == 0) {
                    const int chunk = rr * 128 + u * 16 + (lane >> 2);
                    cm[w * STR1 + (chunk >> 3) * 9 + (chunk & 7)] = s * (1.0f / 16.0f);
                }
            }
        }
    }
    __syncthreads();

    // ---- Phase B: EMA scan. thread = (cl = t>>6, s = t&63), 8 steps each ----
    const int cl = t >> 6, s = t & 63;
    const float g = gamma[ct * CT1 + cl];
    const float omg = 1.0f - g;
    {
        float y = 0.0f;
#pragma unroll
        for (int i = 0; i < 8; ++i)
            y = fmaf(g, y, omg * cm[cl * STR1 + s * 9 + i]);
        carry_s[cl * 64 + s] = y;
    }
    __syncthreads();
    if (t < CT1) {
        const float gg = gamma[ct * CT1 + t];
        float g8 = gg * gg; g8 *= g8; g8 *= g8;            // g^8
        float E = 0.0f;
#pragma unroll
        for (int ss = 0; ss < 64; ++ss) {
            pre_s[t * 64 + ss] = E;                        // state entering seg ss
            E = fmaf(g8, E, carry_s[t * 64 + ss]);
        }
    }
    __syncthreads();
    {
        float y = pre_s[cl * 64 + s];
#pragma unroll
        for (int i = 0; i < 8; ++i) {
            y = fmaf(g, y, omg * cm[cl * STR1 + s * 9 + i]);
            cm[cl * STR1 + s * 9 + i] = y;
        }
    }
    __syncthreads();

    // ---- write e [B][128][N][4]: one contiguous 8 KB run per block ----
    {
        float4* ebase = reinterpret_cast<float4*>(e) + (size_t)(b * 128 + ct) * N;
#pragma unroll
        for (int rr = 0; rr < 2; ++rr) {
            const int n = rr * 256 + t;
            float4 v;
            v.x = cm[0 * STR1 + (n >> 3) * 9 + (n & 7)];
            v.y = cm[1 * STR1 + (n >> 3) * 9 + (n & 7)];
            v.z = cm[2 * STR1 + (n >> 3) * 9 + (n & 7)];
            v.w = cm[3 * STR1 + (n >> 3) * 9 + (n & 7)];
            ebase[n] = v;
        }
    }
}

// ---------------------------------------------------------------------------
// Kernel 2: fused SE + apply, c-half split (grid 2048 = 8 blocks/CU).
// Stage reads e in [B][128][N][4] layout: 16 B granules at 8 KB stride, but
// e is L2/L3-resident (just written) -> cheap. GEMM1 k-split (w1 once/block),
// GEMM2 + gate in LDS, apply 256 c-rows.
// ---------------------------------------------------------------------------
__global__ __launch_bounds__(256) void se_apply_k(
    const float* __restrict__ e, const float* __restrict__ w1t4,
    const float* __restrict__ b1, const float* __restrict__ w2t4,
    const float* __restrict__ b2, const float* __restrict__ x,
    float* __restrict__ out) {
    __shared__ float es[NT2 * C];          // 8 KB  [j][c], c = ct*4+cl
    __shared__ float hs[NT2 * C8];         // 1 KB
    __shared__ float red[4 * NT2 * C8];    // 4 KB  [j][r][o]
    __shared__ float gs[NT2 * GS2];        // 4.2 KB (256 c-rows)
    const int t = threadIdx.x;
    const int bid = blockIdx.x;            // B * 128 * 2 = 2048
    const int chalf = bid & 1;
    const int nt = (bid >> 1) & 127;
    const int b = bid >> 8;
    const int n0 = nt * NT2;

    // stage es[j][C] from e [B][128][N][4]
    {
        const float4* e4 = reinterpret_cast<const float4*>(e) + (size_t)b * 128 * N + n0;
        float4* esw = reinterpret_cast<float4*>(es);
#pragma unroll
        for (int i = 0; i < 2; ++i) {
            const int idx = i * 256 + t;       // 512 = 128 ct x 4 j
            const int ctl = idx & 127;         // consecutive lanes -> consecutive ct
            const int j = idx >> 7;
            esw[j * 128 + ctl] = e4[(size_t)ctl * N + j];
        }
    }
    __syncthreads();

    // GEMM1 k-split: j = k-quarter (wave-uniform), o = lane. w1 once/block.
    {
        const int o = t & 63, j = t >> 6;
        float a0 = 0.f, a1 = 0.f, a2 = 0.f, a3 = 0.f;
        const float4* w1v = reinterpret_cast<const float4*>(w1t4);
        const float4* es4 = reinterpret_cast<const float4*>(es);
        const int k40 = j * 32;
#pragma unroll 8
        for (int kk = 0; kk < 32; ++kk) {
            const int k4 = k40 + kk;
            const float4 wv = w1v[k4 * C8 + o];
            const float4 e0 = es4[0 * 128 + k4];
            const float4 e1 = es4[1 * 128 + k4];
            const float4 e2 = es4[2 * 128 + k4];
            const float4 e3 = es4[3 * 128 + k4];
            a0 = fmaf(wv.x, e0.x, a0); a0 = fmaf(wv.y, e0.y, a0);
            a0 = fmaf(wv.z, e0.z, a0); a0 = fmaf(wv.w, e0.w, a0);
            a1 = fmaf(wv.x, e1.x, a1); a1 = fmaf(wv.y, e1.y, a1);
            a1 = fmaf(wv.z, e1.z, a1); a1 = fmaf(wv.w, e1.w, a1);
            a2 = fmaf(wv.x, e2.x, a2); a2 = fmaf(wv.y, e2.y, a2);
            a2 = fmaf(wv.z, e2.z, a2); a2 = fmaf(wv.w, e2.w, a2);
            a3 = fmaf(wv.x, e3.x, a3); a3 = fmaf(wv.y, e3.y, a3);
            a3 = fmaf(wv.z, e3.z, a3); a3 = fmaf(wv.w, e3.w, a3);
        }
        red[(j * 4 + 0) * 64 + o] = a0;
        red[(j * 4 + 1) * 64 + o] = a1;
        red[(j * 4 + 2) * 64 + o] = a2;
        red[(j * 4 + 3) * 64 + o] = a3;
    }
    __syncthreads();
    {
        const int o = t & 63, r = t >> 6;
        const float h = red[(0 * 4 + r) * 64 + o] + red[(1 * 4 + r) * 64 + o]
                      + red[(2 * 4 + r) * 64 + o] + red[(3 * 4 + r) * 64 + o];
        hs[r * C8 + o] = fmaxf(h + b1[o], 0.f);
    }
    __syncthreads();

    // GEMM2 + sigmoid -> gs[4][256] (this block's c-half only).
    {
        const int c = chalf * 256 + t;
        float acc[NT2];
        const float bb = b2[c];
#pragma unroll
        for (int j = 0; j < NT2; ++j) acc[j] = bb;
        const float4* w2v = reinterpret_cast<const float4*>(w2t4);
        const float4* hs4 = reinterpret_cast<const float4*>(hs);
#pragma unroll
        for (int k4 = 0; k4 < 16; ++k4) {
            const float4 wa = w2v[k4 * C + c];
#pragma unroll
            for (int j = 0; j < NT2; ++j) {
                const float4 hv = hs4[j * 16 + k4];
                acc[j] = fmaf(wa.x, hv.x, acc[j]); acc[j] = fmaf(wa.y, hv.y, acc[j]);
                acc[j] = fmaf(wa.z, hv.z, acc[j]); acc[j] = fmaf(wa.w, hv.w, acc[j]);
            }
        }
#pragma unroll
        for (int j = 0; j < NT2; ++j)
            gs[j * GS2 + t] = 1.0f / (1.0f + __expf(-acc[j]));
    }
    __syncthreads();

    // apply: 256 c-rows (this half), l-range [nt*64, nt*64+64). 16 f4/thread.
    {
        const size_t base4 = (size_t)b * C * (L / 4) + nt * 16;
        const float4* x4 = reinterpret_cast<const float4*>(x);
        float4* o4 = reinterpret_cast<float4*>(out);
#pragma unroll 8
        for (int i = 0; i < 16; ++i) {
            const int p = i * 256 + t;
            const int rloc = p >> 4;       // local c row 0..255
            const int q = p & 15;          // float4 within the 64-float segment
            const float g = gs[(q >> 2) * GS2 + rloc];
            const size_t idx = base4 + (size_t)(chalf * 256 + rloc) * (L / 4) + q;
            float4 v = x4[idx];
            v.x *= g; v.y *= g; v.z *= g; v.w *= g;
            o4[idx] = v;
        }
    }
}

// ---------------------------------------------------------------------------
extern "C" void kernel_launch(void* const* d_in, const int* in_sizes, int n_in,
                              void* d_out, int out_size, void* d_ws, size_t ws_size,
                              hipStream_t stream) {
    const float* x     = (const float*)d_in[0];
    const float* gamma = (const float*)d_in[1];
    const float* w1    = (const float*)d_in[2];
    const float* b1    = (const float*)d_in[3];
    const float* w2    = (const float*)d_in[4];
    const float* b2    = (const float*)d_in[5];
    float* out = (float*)d_out;

    char* ws = (char*)d_ws;
    size_t off = 0;
    float* e    = (float*)(ws + off); off += (size_t)B * N * C * 4;   // 8 MB
    float* w1t4 = (float*)(ws + off); off += (size_t)C8 * C * 4;      // 128 KB
    float* w2t4 = (float*)(ws + off); off += (size_t)C8 * C * 4;      // 128 KB

    // K1: fused pooling + full EMA -> e [B][128][N][4]  (+ weight repack)
    pool_ema_k<<<B * 128, 256, 0, stream>>>(x, gamma, e, w1, w2, w1t4, w2t4);
    // K2: fused SE (gate in LDS) + apply, c-half split (8 blocks/CU)
    se_apply_k<<<B * 256, 256, 0, stream>>>(e, w1t4, b1, w2t4, b2, x, out);
}